// Round 9
// baseline (83.134 us; speedup 1.0000x reference)
//
#include <hip/hip_runtime.h>
#include <hip/hip_bf16.h>
#include <math.h>

#define N_TOK 16384
#define D_DIM 2048
#define E_EXP 64
#define NCH   64                /* K chunks of 32 over full D */
#define NBLK  (N_TOK / 64)      /* 256 blocks, 64-token tiles */

typedef __attribute__((ext_vector_type(8))) short bf16x8;
typedef __attribute__((ext_vector_type(4))) float f32x4;
typedef __attribute__((ext_vector_type(4))) unsigned int u32x4;
typedef __attribute__((ext_vector_type(2))) unsigned int u32x2;

// pack two masked fp32 bit-patterns' high halves into one u32 of 2 bf16
#define PACK2(HI, LO) __builtin_amdgcn_perm((HI), (LO), 0x07060302u)

// LDS x-plane geometry: row stride 40 ushorts (80 B = 20 banks, odd*4 ->
// rows cycle all 8 bank-quads with period 8; reads AND writes <=2-way, free).
#define XROW 40
#define PLANE (64 * XROW)       /* 2560 ushorts per tau plane */
#define BUFSZ (3 * PLANE)       /* 7680 ushorts per dbuf half */

// ---------------------------------------------------------------------------
// pack_w: W fp32 [64][2048] -> exact 3-limb bf16 split, frag-ordered:
// Wp[chunk c][kgroup g][tau][e][8 bf16]. Split is EXACT (masking;
// subtractions Sterbenz-exact); only ml/lm/ll cross terms dropped.
// ---------------------------------------------------------------------------
__global__ void pack_w(const float* __restrict__ W,
                       unsigned short* __restrict__ Wp) {
  const int T = blockIdx.x * 256 + threadIdx.x;   // 16384 = 64c * 4g * 64e
  const int e = T & 63, g = (T >> 6) & 3, c = T >> 8;
  const float* src = W + (size_t)e * D_DIM + c * 32 + g * 8;
  float4 v0 = *(const float4*)src;
  float4 v1 = *(const float4*)(src + 4);
  float vv[8] = {v0.x, v0.y, v0.z, v0.w, v1.x, v1.y, v1.z, v1.w};
  unsigned hu[8], mu[8], lu[8];
#pragma unroll
  for (int j = 0; j < 8; ++j) {
    unsigned u = __float_as_uint(vv[j]);
    unsigned a = u & 0xffff0000u;
    float r = vv[j] - __uint_as_float(a);
    unsigned b = __float_as_uint(r) & 0xffff0000u;
    float r2 = r - __uint_as_float(b);
    unsigned d = __float_as_uint(r2) & 0xffff0000u;
    hu[j] = a; mu[j] = b; lu[j] = d;
  }
  unsigned ph[4], pm[4], pl[4];
#pragma unroll
  for (int q = 0; q < 4; ++q) {     // ascending k pairs: lo in low 16
    ph[q] = PACK2(hu[2 * q + 1], hu[2 * q]);
    pm[q] = PACK2(mu[2 * q + 1], mu[2 * q]);
    pl[q] = PACK2(lu[2 * q + 1], lu[2 * q]);
  }
  const size_t base = (size_t)c * 6144 + g * 1536 + e * 8;  // ushort units
  *(u32x4*)(Wp + base)        = *(u32x4*)ph;   // tau 0
  *(u32x4*)(Wp + base + 512)  = *(u32x4*)pm;   // tau 1
  *(u32x4*)(Wp + base + 1024) = *(u32x4*)pl;   // tau 2
}

// ---------------------------------------------------------------------------
// Fused GEMM + gating epilogue. grid = 256 blocks x 512 thr (8 waves).
// Block = 64 tokens x ALL 64 experts, full K=2048 (no split, no part buf).
// Wave w: tok-quarter th=w>>1 (16 rows), exp-half eh=w&1 (2 nt tiles).
// Per chunk: 12 MFMA/wave (2 tiles x 6 limb terms). x converted in-kernel
// to 3 bf16 LDS planes (dbuf, padded rows, 1 barrier/chunk); W limbs read
// as B-frags straight from L2 (packed by pack_w). Epilogue: acc -> LDS
// logits tile [64][66], then per-token top2/gates (wave0) and per-expert
// p_sum column reduce (wave1) in-block.
// ---------------------------------------------------------------------------
__global__ __launch_bounds__(512)
void fused_router(const float* __restrict__ x,
                  const unsigned short* __restrict__ Wp,
                  float* __restrict__ out,
                  double* __restrict__ blk_ps,     // [256][64]
                  double* __restrict__ blk_z,      // [256]
                  unsigned* __restrict__ freq) {
  __shared__ __align__(16) unsigned short s_x[2 * BUFSZ];  // 30.7 KB
  __shared__ float s_l[64 * 66];                           // 16.9 KB
  __shared__ unsigned hist[64];
  const int tid  = threadIdx.x;
  const int lane = tid & 63;
  const int w    = tid >> 6;
  const int th   = w >> 1;            // token quarter (0..3)
  const int eh   = w & 1;             // expert half (0/1)
  const int T0   = blockIdx.x * 64;

  if (tid < 64) hist[tid] = 0u;

  // conversion role: every thread converts 4 floats per chunk.
  // row crow = tid>>3 (0..63), k-slot cs = tid&7 (4 floats = 8B bf16 out)
  const int crow = tid >> 3;
  const int cs   = tid & 7;
  const float* xg = x + (size_t)(T0 + crow) * D_DIM + cs * 4;
  const int wbase = crow * XROW + cs * 4;            // ushort units

  // A-frag read: row = th*16 + (lane&15), kgroup g = lane>>4
  const int arow  = th * 16 + (lane & 15);
  const int abase = arow * XROW + (lane >> 4) * 8;
  // B-frag lane offset: g*1536 + e*8 (ushort), e = eh*32 + nt*16 + (lane&15)
  const unsigned short* bp =
      Wp + (lane >> 4) * 1536 + (eh * 32 + (lane & 15)) * 8;

  f32x4 acc[2];
  acc[0] = (f32x4)0.f;
  acc[1] = (f32x4)0.f;

#define CVT4(BUF, V)                                                        \
  do {                                                                      \
    float vv[4] = {(V).x, (V).y, (V).z, (V).w};                             \
    unsigned hu[4], mu[4], lu[4];                                           \
    _Pragma("unroll") for (int j = 0; j < 4; ++j) {                         \
      unsigned u = __float_as_uint(vv[j]);                                  \
      unsigned a = u & 0xffff0000u;                                         \
      float r = vv[j] - __uint_as_float(a);                                 \
      unsigned b = __float_as_uint(r) & 0xffff0000u;                        \
      float r2 = r - __uint_as_float(b);                                    \
      unsigned d = __float_as_uint(r2) & 0xffff0000u;                       \
      hu[j] = a; mu[j] = b; lu[j] = d;                                      \
    }                                                                       \
    u32x2 vh = {PACK2(hu[1], hu[0]), PACK2(hu[3], hu[2])};                  \
    u32x2 vm = {PACK2(mu[1], mu[0]), PACK2(mu[3], mu[2])};                  \
    u32x2 vl = {PACK2(lu[1], lu[0]), PACK2(lu[3], lu[2])};                  \
    *(u32x2*)&s_x[(BUF) * BUFSZ + wbase]             = vh;                  \
    *(u32x2*)&s_x[(BUF) * BUFSZ + PLANE + wbase]     = vm;                  \
    *(u32x2*)&s_x[(BUF) * BUFSZ + 2 * PLANE + wbase] = vl;                  \
  } while (0)

  // prolog: chunk 0 -> buf 0; prefetch chunk 1
  float4 rx = *(const float4*)xg;
  CVT4(0, rx);
  rx = *(const float4*)(xg + 32);
  __syncthreads();

#pragma unroll 1
  for (int c = 0; c < NCH; ++c) {
    const int buf = c & 1;
    if (c + 1 < NCH) CVT4(buf ^ 1, rx);              // regs hold chunk c+1
    if (c + 2 < NCH) rx = *(const float4*)(xg + (c + 2) * 32);
    // B-frags for chunk c (L2-resident packed W)
    bf16x8 B0h = *(const bf16x8*)(bp);
    bf16x8 B0m = *(const bf16x8*)(bp + 512);
    bf16x8 B0l = *(const bf16x8*)(bp + 1024);
    bf16x8 B1h = *(const bf16x8*)(bp + 128);
    bf16x8 B1m = *(const bf16x8*)(bp + 128 + 512);
    bf16x8 B1l = *(const bf16x8*)(bp + 128 + 1024);
    // A-frags from LDS (padded rows: conflict-free)
    const unsigned short* ab = &s_x[buf * BUFSZ + abase];
    bf16x8 Ah = *(const bf16x8*)(ab);
    bf16x8 Am = *(const bf16x8*)(ab + PLANE);
    bf16x8 Al = *(const bf16x8*)(ab + 2 * PLANE);

#define MM(BH, BM, BL, ACC)                                                   \
    ACC = __builtin_amdgcn_mfma_f32_16x16x32_bf16(Ah, BH, ACC, 0, 0, 0);      \
    ACC = __builtin_amdgcn_mfma_f32_16x16x32_bf16(Ah, BM, ACC, 0, 0, 0);      \
    ACC = __builtin_amdgcn_mfma_f32_16x16x32_bf16(Am, BH, ACC, 0, 0, 0);      \
    ACC = __builtin_amdgcn_mfma_f32_16x16x32_bf16(Ah, BL, ACC, 0, 0, 0);      \
    ACC = __builtin_amdgcn_mfma_f32_16x16x32_bf16(Am, BM, ACC, 0, 0, 0);      \
    ACC = __builtin_amdgcn_mfma_f32_16x16x32_bf16(Al, BH, ACC, 0, 0, 0)

    MM(B0h, B0m, B0l, acc[0]);
    MM(B1h, B1m, B1l, acc[1]);
#undef MM
    bp += 6144;
    __syncthreads();
  }
#undef CVT4

  // ---- scatter acc into LDS logits tile [64 tok][66] ----
  // C/D: col = lane&15, row = (lane>>4)*4 + rr   [m89-verified]
  {
    const int tok = th * 16 + (lane >> 4) * 4;
    const int ex  = eh * 32 + (lane & 15);
#pragma unroll
    for (int rr = 0; rr < 4; ++rr) {
      s_l[(tok + rr) * 66 + ex]      = acc[0][rr];
      s_l[(tok + rr) * 66 + ex + 16] = acc[1][rr];
    }
  }
  __syncthreads();

  // ---- phase 1 (wave 0): per-token softmax stats, top-2, gates ----
  if (tid < 64) {
    const int t = tid;
    float m = -3.402823466e38f;
#pragma unroll
    for (int e = 0; e < 64; ++e) m = fmaxf(m, s_l[t * 66 + e]);
    float sum = 0.f;
#pragma unroll
    for (int e = 0; e < 64; ++e) sum += __expf(s_l[t * 66 + e] - m);
    const float lse = m + __logf(sum);
    const float inv = 1.0f / sum;
    s_l[t * 66 + 64] = m;
    s_l[t * 66 + 65] = inv;

    // top-2 scan, strict > keeps lowest index on ties (lax.top_k)
    float v0 = s_l[t * 66 + 0], v1 = -3.402823466e38f;
    int i0 = 0, i1 = 0;
#pragma unroll
    for (int e = 1; e < 64; ++e) {
      float le = s_l[t * 66 + e];
      bool g0 = le > v0;
      bool g1 = le > v1;
      float nv1 = g0 ? v0 : (g1 ? le : v1);
      int   ni1 = g0 ? i0 : (g1 ? e  : i1);
      v0 = g0 ? le : v0;
      i0 = g0 ? e  : i0;
      v1 = nv1; i1 = ni1;
    }
    float dd = __expf(v1 - v0);
    float g0 = 1.0f / (1.0f + dd);
    float g1 = dd * g0;

    const int tg = T0 + t;
    out[tg * 2 + 0] = (float)i0;
    out[tg * 2 + 1] = (float)i1;
    out[2 * N_TOK + tg * 2 + 0] = g0;
    out[2 * N_TOK + tg * 2 + 1] = g1;

    atomicAdd(&hist[i0], 1u);
    atomicAdd(&hist[i1], 1u);

    // lse^2 wave reduce -> blk_z
    float z = lse * lse;
    z += __shfl_xor(z, 32, 64);
    z += __shfl_xor(z, 16, 64);
    z += __shfl_xor(z, 8, 64);
    z += __shfl_xor(z, 4, 64);
    z += __shfl_xor(z, 2, 64);
    z += __shfl_xor(z, 1, 64);
    if (lane == 0) blk_z[blockIdx.x] = (double)z;
  }
  __syncthreads();

  // ---- phase 2 (wave 1): per-expert prob column sums ----
  if (w == 1) {
    const int e = lane;
    float cs2 = 0.f;
#pragma unroll 8
    for (int t = 0; t < 64; ++t) {
      float m   = s_l[t * 66 + 64];
      float inv = s_l[t * 66 + 65];
      cs2 += __expf(s_l[t * 66 + e] - m) * inv;
    }
    blk_ps[(size_t)blockIdx.x * 64 + e] = (double)cs2;
  }
  // ---- phase 3 (wave 0): freq flush ----
  if (tid < 64 && hist[tid]) atomicAdd(&freq[tid], hist[tid]);
}

// ---------------------------------------------------------------------------
// Finalize: sum per-block partials, switchloss + 0.1*z_loss (1 block, 64 thr)
// ---------------------------------------------------------------------------
__global__ void finalize(const double* __restrict__ blk_ps,
                         const double* __restrict__ blk_z,
                         const unsigned* __restrict__ freq,
                         float* __restrict__ out_loss) {
  const int lane = threadIdx.x;
  double p = 0.0;
  for (int b = 0; b < 256; ++b) p += blk_ps[(size_t)b * 64 + lane];
  double zt = 0.0;
#pragma unroll
  for (int b = 0; b < 4; ++b) zt += blk_z[lane * 4 + b];
#pragma unroll
  for (int off = 32; off >= 1; off >>= 1) zt += __shfl_xor(zt, off, 64);

  double f = (double)freq[lane];
  double pa = fabs(p);
  double fa = fabs(f);
#pragma unroll
  for (int off = 32; off >= 1; off >>= 1) {
    pa += __shfl_xor(pa, off, 64);
    fa += __shfl_xor(fa, off, 64);
  }
  pa = pa > 1e-12 ? pa : 1e-12;
  fa = fa > 1e-12 ? fa : 1e-12;

  double s = (p / pa) * (f / fa);
#pragma unroll
  for (int off = 32; off >= 1; off >>= 1) s += __shfl_xor(s, off, 64);

  if (lane == 0) {
    double switchloss = 64.0 * s;
    double z_loss = zt / (double)N_TOK;
    out_loss[0] = (float)(switchloss + 0.1 * z_loss);
  }
}

extern "C" void kernel_launch(void* const* d_in, const int* in_sizes, int n_in,
                              void* d_out, int out_size, void* d_ws, size_t ws_size,
                              hipStream_t stream) {
  const float* x = (const float*)d_in[0];
  const float* W = (const float*)d_in[1];
  float* out = (float*)d_out;

  double* blk_ps = (double*)d_ws;                        // 128 KB
  double* blk_z  = blk_ps + 256 * 64;                    // 2 KB
  unsigned* freq = (unsigned*)(blk_z + 256);             // 256 B
  size_t woff = (256 * 64 * 8 + 256 * 8 + 64 * 4 + 255) & ~(size_t)255;
  unsigned short* Wp = (unsigned short*)((char*)d_ws + woff);  // 768 KB

  hipMemsetAsync(freq, 0, 64 * sizeof(unsigned), stream);

  pack_w<<<64, 256, 0, stream>>>(W, Wp);
  fused_router<<<NBLK, 512, 0, stream>>>(x, Wp, out, blk_ps, blk_z, freq);
  finalize<<<1, 64, 0, stream>>>(blk_ps, blk_z, freq, out + 4 * N_TOK);
}

// Round 10
// 68.073 us; speedup vs baseline: 1.2213x; 1.2213x over previous
//
#include <hip/hip_runtime.h>
#include <hip/hip_bf16.h>
#include <math.h>

#define N_TOK 16384
#define D_DIM 2048
#define E_EXP 64
#define KQ    512               /* K per wave (quarter split) */
#define NCHQ  16                /* K-chunks of 32 per wave */
#define NBLK  512               /* 32-token tiles */

typedef __attribute__((ext_vector_type(8))) short bf16x8;
typedef __attribute__((ext_vector_type(16))) float f32x16;
typedef __attribute__((ext_vector_type(4))) unsigned int u32x4;

// pack two masked fp32 bit-patterns' high halves into one u32 of 2 bf16
#define PACK2(HI, LO) __builtin_amdgcn_perm((HI), (LO), 0x07060302u)

typedef union { unsigned u[4]; bf16x8 v; } b8u;

// ---------------------------------------------------------------------------
// pack_w: W fp32 [64][2048] -> exact 3-limb bf16 split, frag-ordered for
// 32x32x16 B-frags: Wp[c 64][ks 2][tau 3][kgrp 2][e 64][8]  (ushort units:
// off = c*6144 + ks*3072 + tau*1024 + kgrp*512 + e*8). Split is EXACT
// (masking; subtractions Sterbenz-exact); only ml/lm/ll cross terms dropped.
// ---------------------------------------------------------------------------
__global__ void pack_w(const float* __restrict__ W,
                       unsigned short* __restrict__ Wp) {
  const int T = blockIdx.x * 256 + threadIdx.x;   // 16384 = 64c * 4j * 64e
  const int e = T & 63, j = (T >> 6) & 3, c = T >> 8;
  const float* src = W + (size_t)e * D_DIM + c * 32 + j * 8;
  float4 v0 = *(const float4*)src;
  float4 v1 = *(const float4*)(src + 4);
  float vv[8] = {v0.x, v0.y, v0.z, v0.w, v1.x, v1.y, v1.z, v1.w};
  unsigned hu[8], mu[8], lu[8];
#pragma unroll
  for (int q = 0; q < 8; ++q) {
    unsigned u = __float_as_uint(vv[q]);
    unsigned a = u & 0xffff0000u;
    float r = vv[q] - __uint_as_float(a);
    unsigned b = __float_as_uint(r) & 0xffff0000u;
    float r2 = r - __uint_as_float(b);
    unsigned d = __float_as_uint(r2) & 0xffff0000u;
    hu[q] = a; mu[q] = b; lu[q] = d;
  }
  u32x4 ph, pm, pl;
#pragma unroll
  for (int q = 0; q < 4; ++q) {     // ascending k pairs: lo k in low 16
    ph[q] = PACK2(hu[2 * q + 1], hu[2 * q]);
    pm[q] = PACK2(mu[2 * q + 1], mu[2 * q]);
    pl[q] = PACK2(lu[2 * q + 1], lu[2 * q]);
  }
  const size_t base = (size_t)c * 6144 + (j >> 1) * 3072 + (j & 1) * 512 + e * 8;
  *(u32x4*)(Wp + base)        = ph;   // tau 0
  *(u32x4*)(Wp + base + 1024) = pm;   // tau 1
  *(u32x4*)(Wp + base + 2048) = pl;   // tau 2
}

// ---------------------------------------------------------------------------
// Fused GEMM + gating. grid = 512 blocks x 256 thr (4 waves). Block =
// 32 tokens x 64 experts; wave kq = tid>>6 owns K-quarter [kq*512, +512).
// MAIN LOOP HAS NO LDS AND NO BARRIERS: each lane gather-loads its own
// A-data (row = lane&31, kgroup = lane>>5 -- the 32x32x16 fragment map),
// limb-splits in registers, and feeds mfma_f32_32x32x16_bf16 directly.
// B-frags stream from L2 (packed by pack_w). K-quarter partials combined
// once via LDS at the end; epilogue in-block (R9-proven logic).
// ---------------------------------------------------------------------------
__global__ __launch_bounds__(256)
void fused_router(const float* __restrict__ x,
                  const unsigned short* __restrict__ Wp,
                  float* __restrict__ out,
                  double* __restrict__ blk_ps,     // [512][64]
                  double* __restrict__ blk_z,      // [512]
                  unsigned* __restrict__ freq) {
  __shared__ float s_c[4][32][66];                 // padded: banks 2-way max
  __shared__ float s_m[32], s_inv[32];
  __shared__ unsigned hist[64];
  const int tid  = threadIdx.x;
  const int lane = tid & 63;
  const int kq   = tid >> 6;
  const int T0   = blockIdx.x * 32;
  if (tid < 64) hist[tid] = 0u;

  const int r  = lane & 31;       // token row within tile / expert col
  const int kg = lane >> 5;       // k-group (0/1) within K=16 step
  const float* xg = x + (size_t)(T0 + r) * D_DIM + kq * KQ + kg * 8;
  const unsigned short* bp =
      Wp + (size_t)(kq * NCHQ) * 6144 + kg * 512 + r * 8;

  f32x16 acc0 = (f32x16)0.f;      // experts 0..31
  f32x16 acc1 = (f32x16)0.f;      // experts 32..63

#define CVT8(V0, V1, OH, OM, OL)                                            \
  do {                                                                      \
    float vv[8] = {(V0).x, (V0).y, (V0).z, (V0).w,                          \
                   (V1).x, (V1).y, (V1).z, (V1).w};                         \
    unsigned hu[8], mu[8], lu[8];                                           \
    _Pragma("unroll") for (int q = 0; q < 8; ++q) {                         \
      unsigned u = __float_as_uint(vv[q]);                                  \
      unsigned a = u & 0xffff0000u;                                         \
      float rr = vv[q] - __uint_as_float(a);                                \
      unsigned b = __float_as_uint(rr) & 0xffff0000u;                       \
      float r2 = rr - __uint_as_float(b);                                   \
      unsigned d = __float_as_uint(r2) & 0xffff0000u;                       \
      hu[q] = a; mu[q] = b; lu[q] = d;                                      \
    }                                                                       \
    b8u th, tm, tl;                                                         \
    _Pragma("unroll") for (int q = 0; q < 4; ++q) {                         \
      th.u[q] = PACK2(hu[2 * q + 1], hu[2 * q]);                            \
      tm.u[q] = PACK2(mu[2 * q + 1], mu[2 * q]);                            \
      tl.u[q] = PACK2(lu[2 * q + 1], lu[2 * q]);                            \
    }                                                                       \
    OH = th.v; OM = tm.v; OL = tl.v;                                        \
  } while (0)

#define MM6(AH, AM, AL, BH, BM, BL, ACC)                                      \
    ACC = __builtin_amdgcn_mfma_f32_32x32x16_bf16(AH, BH, ACC, 0, 0, 0);      \
    ACC = __builtin_amdgcn_mfma_f32_32x32x16_bf16(AH, BM, ACC, 0, 0, 0);      \
    ACC = __builtin_amdgcn_mfma_f32_32x32x16_bf16(AM, BH, ACC, 0, 0, 0);      \
    ACC = __builtin_amdgcn_mfma_f32_32x32x16_bf16(AH, BL, ACC, 0, 0, 0);      \
    ACC = __builtin_amdgcn_mfma_f32_32x32x16_bf16(AM, BM, ACC, 0, 0, 0);      \
    ACC = __builtin_amdgcn_mfma_f32_32x32x16_bf16(AL, BH, ACC, 0, 0, 0)

#pragma unroll 1
  for (int c = 0; c < NCHQ; ++c) {
    const float* xc = xg + c * 32;
    // x gather: 16 floats (rows strided 8KB; lanes r and r+32 share lines)
    float4 xa0 = *(const float4*)(xc);
    float4 xa1 = *(const float4*)(xc + 4);        // kstep 0
    float4 xb0 = *(const float4*)(xc + 16);
    float4 xb1 = *(const float4*)(xc + 20);       // kstep 1
    // B-frags (coalesced 1KB streams from L2)
    const unsigned short* bc = bp + (size_t)c * 6144;
    bf16x8 B00h = *(const bf16x8*)(bc);
    bf16x8 B00m = *(const bf16x8*)(bc + 1024);
    bf16x8 B00l = *(const bf16x8*)(bc + 2048);
    bf16x8 B01h = *(const bf16x8*)(bc + 256);
    bf16x8 B01m = *(const bf16x8*)(bc + 256 + 1024);
    bf16x8 B01l = *(const bf16x8*)(bc + 256 + 2048);
    bf16x8 B10h = *(const bf16x8*)(bc + 3072);
    bf16x8 B10m = *(const bf16x8*)(bc + 3072 + 1024);
    bf16x8 B10l = *(const bf16x8*)(bc + 3072 + 2048);
    bf16x8 B11h = *(const bf16x8*)(bc + 3072 + 256);
    bf16x8 B11m = *(const bf16x8*)(bc + 3072 + 256 + 1024);
    bf16x8 B11l = *(const bf16x8*)(bc + 3072 + 256 + 2048);
    // in-register limb split (VALU; overlaps loads & other waves' MFMA)
    bf16x8 A0h, A0m, A0l, A1h, A1m, A1l;
    CVT8(xa0, xa1, A0h, A0m, A0l);
    CVT8(xb0, xb1, A1h, A1m, A1l);
    // 24 MFMA
    MM6(A0h, A0m, A0l, B00h, B00m, B00l, acc0);
    MM6(A0h, A0m, A0l, B01h, B01m, B01l, acc1);
    MM6(A1h, A1m, A1l, B10h, B10m, B10l, acc0);
    MM6(A1h, A1m, A1l, B11h, B11m, B11l, acc1);
  }
#undef MM6
#undef CVT8

  // ---- scatter K-quarter partials: C/D row = (reg&3)+8*(reg>>2)+4*kg ----
#pragma unroll
  for (int reg = 0; reg < 16; ++reg) {
    const int tl = (reg & 3) + 8 * (reg >> 2) + 4 * kg;
    s_c[kq][tl][r]      = acc0[reg];
    s_c[kq][tl][32 + r] = acc1[reg];
  }
  __syncthreads();

  // ---- combine 4 K-quarters: thread = (t = tid>>3, 8 experts) ----
  {
    const int t = tid >> 3, e0 = (tid & 7) * 8;
#pragma unroll
    for (int q = 0; q < 8; ++q) {
      const int e = e0 + q;
      s_c[0][t][e] = s_c[0][t][e] + s_c[1][t][e] + s_c[2][t][e] + s_c[3][t][e];
    }
  }
  __syncthreads();

  // ---- per-token: softmax stats, top-2, gates (R9-proven) ----
  if (tid < 32) {
    const int t = tid;
    float m = -3.402823466e38f;
#pragma unroll
    for (int e = 0; e < 64; ++e) m = fmaxf(m, s_c[0][t][e]);
    float sum = 0.f;
#pragma unroll
    for (int e = 0; e < 64; ++e) sum += __expf(s_c[0][t][e] - m);
    const float lse = m + __logf(sum);
    const float inv = 1.0f / sum;
    s_m[t] = m;
    s_inv[t] = inv;

    float v0 = s_c[0][t][0], v1 = -3.402823466e38f;
    int i0 = 0, i1 = 0;
#pragma unroll
    for (int e = 1; e < 64; ++e) {
      float le = s_c[0][t][e];
      bool g0 = le > v0;
      bool g1 = le > v1;
      float nv1 = g0 ? v0 : (g1 ? le : v1);
      int   ni1 = g0 ? i0 : (g1 ? e  : i1);
      v0 = g0 ? le : v0;
      i0 = g0 ? e  : i0;
      v1 = nv1; i1 = ni1;
    }
    float dd = __expf(v1 - v0);
    float g0 = 1.0f / (1.0f + dd);
    float g1 = dd * g0;

    const int tg = T0 + t;
    out[tg * 2 + 0] = (float)i0;
    out[tg * 2 + 1] = (float)i1;
    out[2 * N_TOK + tg * 2 + 0] = g0;
    out[2 * N_TOK + tg * 2 + 1] = g1;

    atomicAdd(&hist[i0], 1u);
    atomicAdd(&hist[i1], 1u);

    // lse^2 reduce over lanes 0..31 (offsets < 32 stay in-range)
    float z = lse * lse;
    z += __shfl_xor(z, 16, 64);
    z += __shfl_xor(z, 8, 64);
    z += __shfl_xor(z, 4, 64);
    z += __shfl_xor(z, 2, 64);
    z += __shfl_xor(z, 1, 64);
    if (tid == 0) blk_z[blockIdx.x] = (double)z;
  }
  __syncthreads();

  // ---- per-expert prob column sums (wave 1) + freq flush ----
  if (tid >= 64 && tid < 128) {
    const int e = tid - 64;
    float cs2 = 0.f;
#pragma unroll 8
    for (int t = 0; t < 32; ++t)
      cs2 += __expf(s_c[0][t][e] - s_m[t]) * s_inv[t];
    blk_ps[(size_t)blockIdx.x * 64 + e] = (double)cs2;
  }
  if (tid < 64 && hist[tid]) atomicAdd(&freq[tid], hist[tid]);
}

// ---------------------------------------------------------------------------
// Finalize: sum per-block partials, switchloss + 0.1*z_loss (1 block, 64 thr)
// ---------------------------------------------------------------------------
__global__ void finalize(const double* __restrict__ blk_ps,
                         const double* __restrict__ blk_z,
                         const unsigned* __restrict__ freq,
                         float* __restrict__ out_loss) {
  const int lane = threadIdx.x;
  double p = 0.0;
  for (int b = 0; b < NBLK; ++b) p += blk_ps[(size_t)b * 64 + lane];
  double zt = 0.0;
#pragma unroll
  for (int b = 0; b < NBLK / 64; ++b) zt += blk_z[lane * (NBLK / 64) + b];
#pragma unroll
  for (int off = 32; off >= 1; off >>= 1) zt += __shfl_xor(zt, off, 64);

  double f = (double)freq[lane];
  double pa = fabs(p);
  double fa = fabs(f);
#pragma unroll
  for (int off = 32; off >= 1; off >>= 1) {
    pa += __shfl_xor(pa, off, 64);
    fa += __shfl_xor(fa, off, 64);
  }
  pa = pa > 1e-12 ? pa : 1e-12;
  fa = fa > 1e-12 ? fa : 1e-12;

  double s = (p / pa) * (f / fa);
#pragma unroll
  for (int off = 32; off >= 1; off >>= 1) s += __shfl_xor(s, off, 64);

  if (lane == 0) {
    double switchloss = 64.0 * s;
    double z_loss = zt / (double)N_TOK;
    out_loss[0] = (float)(switchloss + 0.1 * z_loss);
  }
}

extern "C" void kernel_launch(void* const* d_in, const int* in_sizes, int n_in,
                              void* d_out, int out_size, void* d_ws, size_t ws_size,
                              hipStream_t stream) {
  const float* x = (const float*)d_in[0];
  const float* W = (const float*)d_in[1];
  float* out = (float*)d_out;

  double* blk_ps = (double*)d_ws;                        // 512*64*8 = 256 KB
  double* blk_z  = blk_ps + NBLK * 64;                   // 4 KB
  unsigned* freq = (unsigned*)(blk_z + NBLK);            // 256 B
  size_t woff = (NBLK * 64 * 8 + NBLK * 8 + 64 * 4 + 255) & ~(size_t)255;
  unsigned short* Wp = (unsigned short*)((char*)d_ws + woff);  // 768 KB

  hipMemsetAsync(freq, 0, 64 * sizeof(unsigned), stream);

  pack_w<<<64, 256, 0, stream>>>(W, Wp);
  fused_router<<<NBLK, 256, 0, stream>>>(x, Wp, out, blk_ps, blk_z, freq);
  finalize<<<1, 64, 0, stream>>>(blk_ps, blk_z, freq, out + 4 * N_TOK);
}

// Round 11
// 56.944 us; speedup vs baseline: 1.4599x; 1.1954x over previous
//
#include <hip/hip_runtime.h>
#include <hip/hip_bf16.h>
#include <math.h>

#define N_TOK 16384
#define D_DIM 2048
#define E_EXP 64
#define KQ    256               /* K per wave (eighth split) */
#define NCHW  8                 /* K-chunks of 32 per wave */
#define NBLK  256               /* 64-token tiles, 1 block/CU */

typedef __attribute__((ext_vector_type(8))) short bf16x8;
typedef __attribute__((ext_vector_type(16))) float f32x16;
typedef __attribute__((ext_vector_type(4))) unsigned int u32x4;

// pack two masked fp32 bit-patterns' high halves into one u32 of 2 bf16
#define PACK2(HI, LO) __builtin_amdgcn_perm((HI), (LO), 0x07060302u)

typedef union { unsigned u[4]; bf16x8 v; } b8u;

// ---------------------------------------------------------------------------
// pack_w: W fp32 [64][2048] -> exact 3-limb bf16 split, frag-ordered for
// 32x32x16 B-frags: ushort off = c*6144 + ks*3072 + tau*1024 + kgrp*512 + e*8.
// Split is EXACT (masking; subtractions Sterbenz-exact); only ml/lm/ll
// cross terms dropped (~2^-23 rel). Identical to R10 (verified).
// ---------------------------------------------------------------------------
__global__ void pack_w(const float* __restrict__ W,
                       unsigned short* __restrict__ Wp) {
  const int T = blockIdx.x * 256 + threadIdx.x;   // 16384 = 64c * 4j * 64e
  const int e = T & 63, j = (T >> 6) & 3, c = T >> 8;
  const float* src = W + (size_t)e * D_DIM + c * 32 + j * 8;
  float4 v0 = *(const float4*)src;
  float4 v1 = *(const float4*)(src + 4);
  float vv[8] = {v0.x, v0.y, v0.z, v0.w, v1.x, v1.y, v1.z, v1.w};
  unsigned hu[8], mu[8], lu[8];
#pragma unroll
  for (int q = 0; q < 8; ++q) {
    unsigned u = __float_as_uint(vv[q]);
    unsigned a = u & 0xffff0000u;
    float r = vv[q] - __uint_as_float(a);
    unsigned b = __float_as_uint(r) & 0xffff0000u;
    float r2 = r - __uint_as_float(b);
    unsigned d = __float_as_uint(r2) & 0xffff0000u;
    hu[q] = a; mu[q] = b; lu[q] = d;
  }
  u32x4 ph, pm, pl;
#pragma unroll
  for (int q = 0; q < 4; ++q) {     // ascending k pairs: lo k in low 16
    ph[q] = PACK2(hu[2 * q + 1], hu[2 * q]);
    pm[q] = PACK2(mu[2 * q + 1], mu[2 * q]);
    pl[q] = PACK2(lu[2 * q + 1], lu[2 * q]);
  }
  const size_t base = (size_t)c * 6144 + (j >> 1) * 3072 + (j & 1) * 512 + e * 8;
  *(u32x4*)(Wp + base)        = ph;   // tau 0
  *(u32x4*)(Wp + base + 1024) = pm;   // tau 1
  *(u32x4*)(Wp + base + 2048) = pl;   // tau 2
}

// ---------------------------------------------------------------------------
// Fused GEMM + gating. grid = 256 blocks x 512 thr (8 waves). Block =
// 64 tokens x 64 experts; wave kq owns K-eighth [kq*256, +256).
// MAIN LOOP: NO LDS, NO BARRIERS. Lane gather-loads its A rows (row=lane&31,
// kgroup=lane>>5 -- 32x32x16 fragment map), limb-splits in regs, feeds
// mfma_f32_32x32x16_bf16. B streams from L2 (196MB total: half of R10).
// Explicit 2-state x prefetch (static reg names, rule-20): chunk c+1's
// x-loads issue before chunk c's CVT+48 MFMA (~600cy cover). End: staged
// 2-slot LDS combine of 8 K-partials, then in-block epilogue (R9-proven).
// ---------------------------------------------------------------------------
struct XS { float4 a0, a1, b0, b1, c0, c1, d0, d1; };

__global__ __launch_bounds__(512)
void fused_router(const float* __restrict__ x,
                  const unsigned short* __restrict__ Wp,
                  float* __restrict__ out,
                  double* __restrict__ blk_ps,     // [256][64]
                  double* __restrict__ blk_z,      // [256]
                  unsigned* __restrict__ freq) {
  __shared__ float s_c[2][64][66];                 // 33.8 KB, staged combine
  __shared__ float s_m[64], s_inv[64];
  __shared__ unsigned hist[64];
  const int tid  = threadIdx.x;
  const int lane = tid & 63;
  const int kq   = tid >> 6;      // wave = K-eighth
  const int T0   = blockIdx.x * 64;
  if (tid < 64) hist[tid] = 0u;

  const int r  = lane & 31;       // token row within 32-tile / expert col
  const int kg = lane >> 5;       // k-group (0/1) within K=16 step
  const float* xg0 = x + (size_t)(T0 + r) * D_DIM + kq * KQ + kg * 8;
  const float* xg1 = xg0 + (size_t)32 * D_DIM;
  const unsigned short* bp =
      Wp + (size_t)(kq * NCHW) * 6144 + kg * 512 + r * 8;

  f32x16 acc00 = (f32x16)0.f, acc01 = (f32x16)0.f;   // rows 0-31 x e 0-31/32-63
  f32x16 acc10 = (f32x16)0.f, acc11 = (f32x16)0.f;   // rows 32-63

#define CVT8(V0, V1, OH, OM, OL)                                            \
  do {                                                                      \
    float vv[8] = {(V0).x, (V0).y, (V0).z, (V0).w,                          \
                   (V1).x, (V1).y, (V1).z, (V1).w};                         \
    unsigned hu[8], mu[8], lu[8];                                           \
    _Pragma("unroll") for (int q = 0; q < 8; ++q) {                         \
      unsigned u = __float_as_uint(vv[q]);                                  \
      unsigned a = u & 0xffff0000u;                                         \
      float rr = vv[q] - __uint_as_float(a);                                \
      unsigned b = __float_as_uint(rr) & 0xffff0000u;                       \
      float r2 = rr - __uint_as_float(b);                                   \
      unsigned d = __float_as_uint(r2) & 0xffff0000u;                       \
      hu[q] = a; mu[q] = b; lu[q] = d;                                      \
    }                                                                       \
    b8u th, tm, tl;                                                         \
    _Pragma("unroll") for (int q = 0; q < 4; ++q) {                         \
      th.u[q] = PACK2(hu[2 * q + 1], hu[2 * q]);                            \
      tm.u[q] = PACK2(mu[2 * q + 1], mu[2 * q]);                            \
      tl.u[q] = PACK2(lu[2 * q + 1], lu[2 * q]);                            \
    }                                                                       \
    OH = th.v; OM = tm.v; OL = tl.v;                                        \
  } while (0)

#define MM6(AH, AM, AL, BH, BM, BL, ACC)                                      \
    ACC = __builtin_amdgcn_mfma_f32_32x32x16_bf16(AH, BH, ACC, 0, 0, 0);      \
    ACC = __builtin_amdgcn_mfma_f32_32x32x16_bf16(AH, BM, ACC, 0, 0, 0);      \
    ACC = __builtin_amdgcn_mfma_f32_32x32x16_bf16(AM, BH, ACC, 0, 0, 0);      \
    ACC = __builtin_amdgcn_mfma_f32_32x32x16_bf16(AH, BL, ACC, 0, 0, 0);      \
    ACC = __builtin_amdgcn_mfma_f32_32x32x16_bf16(AM, BM, ACC, 0, 0, 0);      \
    ACC = __builtin_amdgcn_mfma_f32_32x32x16_bf16(AL, BH, ACC, 0, 0, 0)

#define LOADX(S, C)                                                         \
  do {                                                                      \
    const float* p0_ = xg0 + (C) * 32;                                      \
    const float* p1_ = xg1 + (C) * 32;                                      \
    S.a0 = *(const float4*)(p0_);      S.a1 = *(const float4*)(p0_ + 4);    \
    S.b0 = *(const float4*)(p0_ + 16); S.b1 = *(const float4*)(p0_ + 20);   \
    S.c0 = *(const float4*)(p1_);      S.c1 = *(const float4*)(p1_ + 4);    \
    S.d0 = *(const float4*)(p1_ + 16); S.d1 = *(const float4*)(p1_ + 20);   \
  } while (0)

#define BODY(C, XU, XN, DOPRE)                                              \
  {                                                                         \
    const unsigned short* bc = bp + (size_t)(C) * 6144;                     \
    bf16x8 B00h = *(const bf16x8*)(bc);                                     \
    bf16x8 B00m = *(const bf16x8*)(bc + 1024);                              \
    bf16x8 B00l = *(const bf16x8*)(bc + 2048);                              \
    bf16x8 B01h = *(const bf16x8*)(bc + 256);                               \
    bf16x8 B01m = *(const bf16x8*)(bc + 256 + 1024);                        \
    bf16x8 B01l = *(const bf16x8*)(bc + 256 + 2048);                        \
    bf16x8 B10h = *(const bf16x8*)(bc + 3072);                              \
    bf16x8 B10m = *(const bf16x8*)(bc + 3072 + 1024);                       \
    bf16x8 B10l = *(const bf16x8*)(bc + 3072 + 2048);                       \
    bf16x8 B11h = *(const bf16x8*)(bc + 3072 + 256);                        \
    bf16x8 B11m = *(const bf16x8*)(bc + 3072 + 256 + 1024);                 \
    bf16x8 B11l = *(const bf16x8*)(bc + 3072 + 256 + 2048);                 \
    if (DOPRE) LOADX(XN, (C) + 1);  /* T14: issue-early, use next iter */   \
    {                                                                       \
      bf16x8 A0h, A0m, A0l, A1h, A1m, A1l;                                  \
      CVT8(XU.a0, XU.a1, A0h, A0m, A0l);   /* rows 0-31, kstep 0 */         \
      CVT8(XU.b0, XU.b1, A1h, A1m, A1l);   /* rows 0-31, kstep 1 */         \
      MM6(A0h, A0m, A0l, B00h, B00m, B00l, acc00);                          \
      MM6(A0h, A0m, A0l, B01h, B01m, B01l, acc01);                          \
      MM6(A1h, A1m, A1l, B10h, B10m, B10l, acc00);                          \
      MM6(A1h, A1m, A1l, B11h, B11m, B11l, acc01);                          \
    }                                                                       \
    {                                                                       \
      bf16x8 A0h, A0m, A0l, A1h, A1m, A1l;                                  \
      CVT8(XU.c0, XU.c1, A0h, A0m, A0l);   /* rows 32-63, kstep 0 */        \
      CVT8(XU.d0, XU.d1, A1h, A1m, A1l);   /* rows 32-63, kstep 1 */        \
      MM6(A0h, A0m, A0l, B00h, B00m, B00l, acc10);                          \
      MM6(A0h, A0m, A0l, B01h, B01m, B01l, acc11);                          \
      MM6(A1h, A1m, A1l, B10h, B10m, B10l, acc10);                          \
      MM6(A1h, A1m, A1l, B11h, B11m, B11l, acc11);                          \
    }                                                                       \
  }

  XS xA, xB;
  LOADX(xA, 0);
#pragma unroll
  for (int cc = 0; cc < NCHW; cc += 2) {
    BODY(cc, xA, xB, (cc + 1) < NCHW);
    BODY(cc + 1, xB, xA, (cc + 2) < NCHW);
  }
#undef BODY
#undef LOADX
#undef MM6
#undef CVT8

  // ---- staged 2-slot combine of 8 K-partials ----
  // C/D row-in-tile = (reg&3) + 8*(reg>>2) + 4*kg  [m74/m101-verified]
  const int slot = kq & 1;
#define SCAT(OP)                                                            \
  _Pragma("unroll") for (int reg = 0; reg < 16; ++reg) {                    \
    const int tl_ = (reg & 3) + 8 * (reg >> 2) + 4 * kg;                    \
    s_c[slot][tl_][r]           OP acc00[reg];                              \
    s_c[slot][tl_][32 + r]      OP acc01[reg];                              \
    s_c[slot][32 + tl_][r]      OP acc10[reg];                              \
    s_c[slot][32 + tl_][32 + r] OP acc11[reg];                              \
  }
  if (kq < 2) SCAT(=);
  __syncthreads();
  if (kq == 2 || kq == 3) SCAT(+=);
  __syncthreads();
  if (kq == 4 || kq == 5) SCAT(+=);
  __syncthreads();
  if (kq == 6 || kq == 7) SCAT(+=);
  __syncthreads();
#undef SCAT
  {   // fold slot1 into slot0: all 512 threads
    const int t = tid >> 3, e0 = (tid & 7) * 8;
#pragma unroll
    for (int q = 0; q < 8; ++q)
      s_c[0][t][e0 + q] += s_c[1][t][e0 + q];
  }
  __syncthreads();

  // ---- per-token: softmax stats, top-2, gates (R9-proven) ----
  if (tid < 64) {
    const int t = tid;
    float m = -3.402823466e38f;
#pragma unroll
    for (int e = 0; e < 64; ++e) m = fmaxf(m, s_c[0][t][e]);
    float sum = 0.f;
#pragma unroll
    for (int e = 0; e < 64; ++e) sum += __expf(s_c[0][t][e] - m);
    const float lse = m + __logf(sum);
    const float inv = 1.0f / sum;
    s_m[t] = m;
    s_inv[t] = inv;

    float v0 = s_c[0][t][0], v1 = -3.402823466e38f;
    int i0 = 0, i1 = 0;
#pragma unroll
    for (int e = 1; e < 64; ++e) {   // strict > keeps lowest idx (lax.top_k)
      float le = s_c[0][t][e];
      bool g0 = le > v0;
      bool g1 = le > v1;
      float nv1 = g0 ? v0 : (g1 ? le : v1);
      int   ni1 = g0 ? i0 : (g1 ? e  : i1);
      v0 = g0 ? le : v0;
      i0 = g0 ? e  : i0;
      v1 = nv1; i1 = ni1;
    }
    float dd = __expf(v1 - v0);
    float g0 = 1.0f / (1.0f + dd);
    float g1 = dd * g0;

    const int tg = T0 + t;
    out[tg * 2 + 0] = (float)i0;
    out[tg * 2 + 1] = (float)i1;
    out[2 * N_TOK + tg * 2 + 0] = g0;
    out[2 * N_TOK + tg * 2 + 1] = g1;

    atomicAdd(&hist[i0], 1u);
    atomicAdd(&hist[i1], 1u);

    float z = lse * lse;
    z += __shfl_xor(z, 32, 64);
    z += __shfl_xor(z, 16, 64);
    z += __shfl_xor(z, 8, 64);
    z += __shfl_xor(z, 4, 64);
    z += __shfl_xor(z, 2, 64);
    z += __shfl_xor(z, 1, 64);
    if (tid == 0) blk_z[blockIdx.x] = (double)z;
  }
  __syncthreads();

  // ---- per-expert prob column sums (wave 1) + freq flush ----
  if (tid >= 64 && tid < 128) {
    const int e = tid - 64;
    float cs2 = 0.f;
#pragma unroll 8
    for (int t = 0; t < 64; ++t)
      cs2 += __expf(s_c[0][t][e] - s_m[t]) * s_inv[t];
    blk_ps[(size_t)blockIdx.x * 64 + e] = (double)cs2;
  }
  if (tid < 64 && hist[tid]) atomicAdd(&freq[tid], hist[tid]);
}

// ---------------------------------------------------------------------------
// Finalize: sum per-block partials, switchloss + 0.1*z_loss (1 block, 64 thr)
// ---------------------------------------------------------------------------
__global__ void finalize(const double* __restrict__ blk_ps,
                         const double* __restrict__ blk_z,
                         const unsigned* __restrict__ freq,
                         float* __restrict__ out_loss) {
  const int lane = threadIdx.x;
  double p = 0.0;
  for (int b = 0; b < NBLK; ++b) p += blk_ps[(size_t)b * 64 + lane];
  double zt = 0.0;
#pragma unroll
  for (int b = 0; b < NBLK / 64; ++b) zt += blk_z[lane * (NBLK / 64) + b];
#pragma unroll
  for (int off = 32; off >= 1; off >>= 1) zt += __shfl_xor(zt, off, 64);

  double f = (double)freq[lane];
  double pa = fabs(p);
  double fa = fabs(f);
#pragma unroll
  for (int off = 32; off >= 1; off >>= 1) {
    pa += __shfl_xor(pa, off, 64);
    fa += __shfl_xor(fa, off, 64);
  }
  pa = pa > 1e-12 ? pa : 1e-12;
  fa = fa > 1e-12 ? fa : 1e-12;

  double s = (p / pa) * (f / fa);
#pragma unroll
  for (int off = 32; off >= 1; off >>= 1) s += __shfl_xor(s, off, 64);

  if (lane == 0) {
    double switchloss = 64.0 * s;
    double z_loss = zt / (double)N_TOK;
    out_loss[0] = (float)(switchloss + 0.1 * z_loss);
  }
}

extern "C" void kernel_launch(void* const* d_in, const int* in_sizes, int n_in,
                              void* d_out, int out_size, void* d_ws, size_t ws_size,
                              hipStream_t stream) {
  const float* x = (const float*)d_in[0];
  const float* W = (const float*)d_in[1];
  float* out = (float*)d_out;

  double* blk_ps = (double*)d_ws;                        // 256*64*8 = 128 KB
  double* blk_z  = blk_ps + NBLK * 64;                   // 2 KB
  unsigned* freq = (unsigned*)(blk_z + NBLK);            // 256 B
  size_t woff = (NBLK * 64 * 8 + NBLK * 8 + 64 * 4 + 255) & ~(size_t)255;
  unsigned short* Wp = (unsigned short*)((char*)d_ws + woff);  // 768 KB

  hipMemsetAsync(freq, 0, 64 * sizeof(unsigned), stream);

  pack_w<<<64, 256, 0, stream>>>(W, Wp);
  fused_router<<<NBLK, 512, 0, stream>>>(x, Wp, out, blk_ps, blk_z, freq);
  finalize<<<1, 64, 0, stream>>>(blk_ps, blk_z, freq, out + 4 * N_TOK);
}